// Round 6
// baseline (352.432 us; speedup 1.0000x reference)
//
#include <hip/hip_runtime.h>
#include <cfloat>
#include <cmath>

#define NROWS 16384
#define DDIM  4096
#define NEXP  64
#define TOPK  8
#define GAP_THRESH 5e-4f

#define KSPLIT 4
#define KPB    (DDIM / KSPLIT)   // 1024 k per block
#define CHUNK  32                // k per LDS chunk
#define NCHUNK (KPB / CHUNK)     // 32
#define RB     128               // rows per block

// ws layout: [Wd 2MB][count 256B][list 64KB][part 16MB]

__global__ __launch_bounds__(256) void prep_kernel(const float* __restrict__ W,
                                                   double* __restrict__ Wd,
                                                   int* __restrict__ count) {
    int t = blockIdx.x * 256 + threadIdx.x;
    Wd[t] = (double)W[t];
    if (t == 0) *count = 0;
}

// async 16B global->LDS (LDS dest = wave-uniform base + lane*16, linear)
__device__ __forceinline__ void gload_lds16(const float* g, float* l) {
    __builtin_amdgcn_global_load_lds(
        (const __attribute__((address_space(1))) unsigned int*)g,
        (__attribute__((address_space(3))) unsigned int*)l,
        16, 0, 0);
}

// ---------------------------------------------------------------------------
// Gate GEMM fp32.  Block = 128 thr (2 waves), tile 128 rows x 64 e x 1024 k.
// Thread = 8 rows x 8 contiguous experts = 64 acc -> 16 b128 per 256 FMAs.
// x LDS [row][32k] row-stride 128B: source-swizzled col (sl^l3), read slot
// q^(tr&7) -> 2-way conflict (free) + 4-way broadcast.  w LDS [e][32k]:
// source-swizzled by segment (sl^seg), read slot q^tc -> conflict-free,
// 16-way broadcast.  3 blocks/CU (48KB LDS) stagger the 2-phase barriers.
// ---------------------------------------------------------------------------
__global__ __launch_bounds__(128) void gate_kernel(
    const float* __restrict__ x,
    const float* __restrict__ W,
    float* __restrict__ part)          // [KSPLIT][NROWS][NEXP]
{
    __shared__ float xT[2][CHUNK * RB];    // 2 x 16 KB : 16 segs of (8row x 32k)
    __shared__ float wT[2][CHUNK * NEXP];  // 2 x  8 KB :  8 segs of (8e   x 32k)

    const int t    = threadIdx.x;          // 0..127
    const int lane = t & 63;
    const int wv   = t >> 6;               // 0..1
    const int h    = blockIdx.x & (KSPLIT - 1);
    const int row0 = (blockIdx.x >> 2) * RB;
    const int k0   = h * KPB;

    const int l3 = lane >> 3;              // row/expert within segment (0..7)
    const int sl = lane & 7;               // 16B slot (0..7)

    // x staging: wave wv covers segments wv*8+j ; lane -> row seg*8+l3,
    // global col-group sl^l3 (so LDS slot sl holds group sl^(row&7))
    const float* gx[8];
#pragma unroll
    for (int j = 0; j < 8; ++j) {
        const int seg = wv * 8 + j;
        gx[j] = x + (size_t)(row0 + seg * 8 + l3) * DDIM + k0 + ((sl ^ l3) << 2);
    }
    // w staging: wave wv covers segments wv*4+j ; lane -> e = seg*8+l3,
    // global col-group sl^seg (LDS slot sl holds group sl^(e>>3))
    const float* gw[4];
#pragma unroll
    for (int j = 0; j < 4; ++j) {
        const int seg = wv * 4 + j;
        gw[j] = W + (size_t)(seg * 8 + l3) * DDIM + k0 + ((sl ^ seg) << 2);
    }

#define STAGE(nb, c) do {                                              \
        const int ko_ = (c) * CHUNK;                                   \
        _Pragma("unroll")                                              \
        for (int j_ = 0; j_ < 8; ++j_)                                 \
            gload_lds16(gx[j_] + ko_, &xT[nb][(wv * 8 + j_) * 256]);   \
        _Pragma("unroll")                                              \
        for (int j_ = 0; j_ < 4; ++j_)                                 \
            gload_lds16(gw[j_] + ko_, &wT[nb][(wv * 4 + j_) * 256]);   \
    } while (0)

    // compute tile: rows tr+16*ri, experts tc*8+ei
    const int tr = t & 15;
    const int tc = t >> 4;                 // 0..7
    int xo[8], wo[8];
#pragma unroll
    for (int q = 0; q < 8; ++q) {          // fully unrolled consumers only
        xo[q] = (q ^ (tr & 7)) << 2;
        wo[q] = (q ^ tc) << 2;
    }

    float acc[8][8] = {};

    STAGE(0, 0);
    __syncthreads();

    int buf = 0;
    for (int c = 0; c < NCHUNK; ++c) {
        if (c + 1 < NCHUNK) STAGE(buf ^ 1, c + 1);   // async, no regs held

        const float* xb = xT[buf];
        const float* wb = wT[buf];
#pragma unroll
        for (int q = 0; q < 8; ++q) {                 // 4 k per quad
            float4 wreg[8];
#pragma unroll
            for (int ei = 0; ei < 8; ++ei)
                wreg[ei] = *reinterpret_cast<const float4*>(
                    wb + (tc * 8 + ei) * 32 + wo[q]);
#pragma unroll
            for (int ri = 0; ri < 8; ++ri) {
                float4 xv = *reinterpret_cast<const float4*>(
                    xb + (tr + 16 * ri) * 32 + xo[q]);
#pragma unroll
                for (int ei = 0; ei < 8; ++ei) {
                    acc[ri][ei] = fmaf(xv.x, wreg[ei].x, acc[ri][ei]);
                    acc[ri][ei] = fmaf(xv.y, wreg[ei].y, acc[ri][ei]);
                    acc[ri][ei] = fmaf(xv.z, wreg[ei].z, acc[ri][ei]);
                    acc[ri][ei] = fmaf(xv.w, wreg[ei].w, acc[ri][ei]);
                }
            }
        }
        __syncthreads();
        buf ^= 1;
    }
#undef STAGE

#pragma unroll
    for (int ri = 0; ri < 8; ++ri) {
        const int row = row0 + tr + 16 * ri;
        float* pp = part + ((size_t)h * NROWS + row) * NEXP + tc * 8;
        *reinterpret_cast<float4*>(pp) =
            make_float4(acc[ri][0], acc[ri][1], acc[ri][2], acc[ri][3]);
        *reinterpret_cast<float4*>(pp + 4) =
            make_float4(acc[ri][4], acc[ri][5], acc[ri][6], acc[ri][7]);
    }
}

// ---------------------------------------------------------------------------
// Reduce + top-9 + sparse softmax + ambiguity flag (proven rounds 3-5).
// ---------------------------------------------------------------------------
__global__ __launch_bounds__(256) void reduce_kernel(
    const float* __restrict__ part,
    const float* __restrict__ b,
    float* __restrict__ outp,
    float* __restrict__ outi,
    int*   __restrict__ count,
    int*   __restrict__ list)
{
    const int lane = threadIdx.x & 63;
    const int w    = threadIdx.x >> 6;
    const int row  = blockIdx.x * 4 + w;

    float orig = b[lane];
#pragma unroll
    for (int h = 0; h < KSPLIT; ++h)
        orig += part[((size_t)h * NROWS + row) * NEXP + lane];

    float cur = orig;
    float vals[9];
    float myidxf = 0.0f;
    bool  sel = false;

#pragma unroll
    for (int i = 0; i < 9; ++i) {
        float m = cur;
#pragma unroll
        for (int off = 32; off > 0; off >>= 1)
            m = fmaxf(m, __shfl_xor(m, off, 64));
        unsigned long long msk = __ballot(cur == m);
        int il = __ffsll((long long)msk) - 1;
        vals[i] = m;
        if (lane == il) { cur = -FLT_MAX; if (i < TOPK) sel = true; }
        if (i < TOPK && lane == i) myidxf = (float)il;
    }

    float ssum = 0.0f;
#pragma unroll
    for (int i = 0; i < TOPK; ++i) ssum += expf(vals[i] - vals[0]);
    float p = sel ? (expf(orig - vals[0]) / ssum) : 0.0f;

    outp[(size_t)row * NEXP + lane] = p;
    if (lane < TOPK) outi[(size_t)row * TOPK + lane] = myidxf;

    float mingap = FLT_MAX;
#pragma unroll
    for (int i = 0; i < 8; ++i) mingap = fminf(mingap, vals[i] - vals[i + 1]);
    if (lane == 0 && mingap < GAP_THRESH) {
        int pos = atomicAdd(count, 1);
        if (pos < NROWS) list[pos] = row;
    }
}

// ---------------------------------------------------------------------------
// fp64 rescue.  NEW: stage the x row into LDS with coalesced per-lane float4
// loads first (round-5 version read x at wave-uniform addresses -> scalar
// path -> ~96us/row).  LDS reads broadcast; Wd rows are per-lane streams.
// ---------------------------------------------------------------------------
__global__ __launch_bounds__(64) void fix_kernel(
    const float*  __restrict__ x,
    const double* __restrict__ Wd,
    const float*  __restrict__ b,
    float* __restrict__ outp,
    float* __restrict__ outi,
    const int* __restrict__ count,
    const int* __restrict__ list)
{
    __shared__ float xs[DDIM];
    const int lane = threadIdx.x;
    const int cnt  = *count;

    for (int i = blockIdx.x; i < cnt; i += gridDim.x) {
        const int row = list[i];

        const float4* xr4 = reinterpret_cast<const float4*>(x + (size_t)row * DDIM);
#pragma unroll
        for (int j = 0; j < DDIM / 4 / 64; ++j)    // 16 coalesced float4 loads
            *reinterpret_cast<float4*>(xs + (j * 64 + lane) * 4) = xr4[j * 64 + lane];
        __syncthreads();

        const double* wp = Wd + (size_t)lane * DDIM;
        double a0 = 0.0, a1 = 0.0, a2 = 0.0, a3 = 0.0;
        for (int k = 0; k < DDIM; k += 4) {
            float4 xv = *reinterpret_cast<const float4*>(xs + k);   // broadcast
            a0 = fma((double)xv.x, wp[k + 0], a0);
            a1 = fma((double)xv.y, wp[k + 1], a1);
            a2 = fma((double)xv.z, wp[k + 2], a2);
            a3 = fma((double)xv.w, wp[k + 3], a3);
        }
        const double orig = ((a0 + a1) + (a2 + a3)) + (double)b[lane];
        double cur = orig;

        double vals[TOPK];
        float  myidxf = 0.0f;
        bool   sel = false;

#pragma unroll
        for (int tt = 0; tt < TOPK; ++tt) {
            double m = cur;
#pragma unroll
            for (int off = 32; off > 0; off >>= 1) {
                double o = __shfl_xor(m, off, 64);
                m = fmax(m, o);
            }
            unsigned long long msk = __ballot(cur == m);
            int il = __ffsll((long long)msk) - 1;
            vals[tt] = m;
            if (lane == il) { cur = -DBL_MAX; sel = true; }
            if (lane == tt)  myidxf = (float)il;
        }

        double ssum = 0.0;
#pragma unroll
        for (int tt = 0; tt < TOPK; ++tt) ssum += exp(vals[tt] - vals[0]);
        float p = sel ? (float)(exp(orig - vals[0]) / ssum) : 0.0f;

        outp[(size_t)row * NEXP + lane] = p;
        if (lane < TOPK) outi[(size_t)row * TOPK + lane] = myidxf;
        __syncthreads();   // xs reused next iteration
    }
}

// ---------------------------------------------------------------------------
// Fallback (tiny ws): per-thread-row full fp64 from f32 W.  Correct, slow.
// ---------------------------------------------------------------------------
__global__ __launch_bounds__(64) void fallback_kernel(
    const float* __restrict__ x,
    const float* __restrict__ W,
    const float* __restrict__ b,
    float* __restrict__ outp,
    float* __restrict__ outi)
{
    const int row = blockIdx.x * 64 + threadIdx.x;
    double lg[64];
#pragma unroll
    for (int e = 0; e < 64; ++e) lg[e] = (double)b[e];
    const float* xr = x + (size_t)row * DDIM;
    for (int k = 0; k < DDIM; k += 4) {
        float4 xa = *reinterpret_cast<const float4*>(xr + k);
        double xd[4] = {(double)xa.x, (double)xa.y, (double)xa.z, (double)xa.w};
#pragma unroll
        for (int e = 0; e < 64; ++e) {
            const float* wp = W + (size_t)e * DDIM + k;
            double a = lg[e];
#pragma unroll
            for (int j = 0; j < 4; ++j) a = fma(xd[j], (double)wp[j], a);
            lg[e] = a;
        }
    }
    unsigned long long selm = 0ull;
    double vals[TOPK]; int idx[TOPK];
#pragma unroll
    for (int i = 0; i < TOPK; ++i) {
        double m = -DBL_MAX; int mi = 0;
#pragma unroll
        for (int e = 0; e < 64; ++e) {
            bool gt = !((selm >> e) & 1ull) && (lg[e] > m);
            m = gt ? lg[e] : m; mi = gt ? e : mi;
        }
        vals[i] = m; idx[i] = mi; selm |= (1ull << mi);
    }
    double ssum = 0.0;
#pragma unroll
    for (int i = 0; i < TOPK; ++i) ssum += exp(vals[i] - vals[0]);
    double inv = 1.0 / ssum;
#pragma unroll
    for (int e = 0; e < 64; ++e)
        outp[(size_t)row * NEXP + e] =
            ((selm >> e) & 1ull) ? (float)(exp(lg[e] - vals[0]) * inv) : 0.0f;
#pragma unroll
    for (int i = 0; i < TOPK; ++i)
        outi[(size_t)row * TOPK + i] = (float)idx[i];
}

// ---------------------------------------------------------------------------
extern "C" void kernel_launch(void* const* d_in, const int* in_sizes, int n_in,
                              void* d_out, int out_size, void* d_ws, size_t ws_size,
                              hipStream_t stream) {
    (void)in_sizes; (void)n_in; (void)out_size;
    const float* x = (const float*)d_in[0];
    const float* W = (const float*)d_in[1];
    const float* b = (const float*)d_in[2];

    float* outp = (float*)d_out;
    float* outi = outp + (size_t)NROWS * NEXP;

    const size_t wd_bytes  = sizeof(double) * (size_t)NEXP * DDIM;          // 2 MB
    const size_t cnt_off   = wd_bytes;
    const size_t list_off  = cnt_off + 256;
    const size_t part_off  = list_off + (size_t)NROWS * sizeof(int);
    const size_t need      = part_off + (size_t)KSPLIT * NROWS * NEXP * sizeof(float);

    if (ws_size >= need) {
        double* Wd   = (double*)d_ws;
        int*    cnt  = (int*)((char*)d_ws + cnt_off);
        int*    list = (int*)((char*)d_ws + list_off);
        float*  part = (float*)((char*)d_ws + part_off);

        prep_kernel<<<(NEXP * DDIM) / 256, 256, 0, stream>>>(W, Wd, cnt);
        gate_kernel<<<(NROWS / RB) * KSPLIT, 128, 0, stream>>>(x, W, part);
        reduce_kernel<<<NROWS / 4, 256, 0, stream>>>(part, b, outp, outi, cnt, list);
        fix_kernel<<<1024, 64, 0, stream>>>(x, Wd, b, outp, outi, cnt, list);
    } else {
        fallback_kernel<<<NROWS / 64, 64, 0, stream>>>(x, W, b, outp, outi);
    }
}